// Round 2
// baseline (5759.936 us; speedup 1.0000x reference)
//
#include <hip/hip_runtime.h>

// 2D-MDLSTM wavefront kernel for MI355X (gfx950), full hi/lo f16-split precision.
// z = [x(256) | h_up(512) | h_left(512)] @ W(1280x2560) + b, gates i,j,f1,f2,o.
// Split: every operand O = Oh + Ol (f16 pair); z-term = AhBh + AlBh + AhBl (fp32 acc).
// Scaling: A-planes *16, B-planes *64 (avoid f16 denormal lo-planes); z = acc/1024 + b.
// 2 cells stacked per wave (M=64); 32 N-slices of 80 cols (16 r-cols x 5 gates, permuted);
// h/c kept in 2-diagonal ring buffers; per-diagonal device-scope flag sync; 128 WGs.

typedef _Float16 f16;
typedef f16   f16x8 __attribute__((ext_vector_type(8)));
typedef float f32x4 __attribute__((ext_vector_type(4)));

#define NWG 128
#define SCL (1.0f/1024.0f)

// workspace layout (bytes); total ~52.7 MiB
#define FLAGS_OFF 0L
#define ZERO_OFF  4096L                 // zeros through BT_OFF (memset prefix)
#define BT_OFF    131072L
#define BT_BYTES  13107200L             // 409600 frags * 16 f16 * 2B (hi/lo interleaved)
#define XG_OFF    (BT_OFF + BT_BYTES)
#define XG_PLANE  8388608L              // elems per plane (1024*32*256)
#define XG_BYTES  (XG_PLANE*4L)
#define HR_OFF    (XG_OFF + XG_BYTES)
#define HR_PLANE  1048576L              // elems per plane (2*32*16384)
#define HR_BYTES  (HR_PLANE*4L)
#define CR_OFF    (HR_OFF + HR_BYTES)
#define CR_BYTES  (HR_PLANE*4L)

// ---------------- prep: gather x -> xg f16 hi/lo planes [cell][b][f] ----------------
// torch-style raw reshape: c = f&15; xd = 4h + (w>>3); yd = (w&7)*16 + (f>>4)
__global__ __launch_bounds__(256) void gather_xg_k(const float* __restrict__ x, f16* __restrict__ xg) {
  int cb = blockIdx.x;                  // cell*32 + b
  int f  = threadIdx.x;
  int cell = cb >> 5, b = cb & 31;
  int hh = cell >> 5, ww = cell & 31;
  int c  = f & 15, fo = f >> 4;
  int xd = hh*4 + (ww >> 3);
  int yd = (ww & 7)*16 + fo;
  float v = x[(((long)b*16 + c)*128 + xd)*128 + yd] * 16.0f;
  f16 hi = (f16)v;
  f16 lo = (f16)(v - (float)hi);
  long o = (long)cb*256 + f;
  xg[o] = hi;
  xg[XG_PLANE + o] = lo;
}

// ---------------- prep: W -> f16 hi/lo frag pairs, column-permuted ----------------
// frag idx = ((s*5+g)*40 + kstep)*64 + lane ; lane -> B[k=kstep*32+(lane>>4)*8+u][n=g*512+s*16+(lane&15)]
__global__ __launch_bounds__(256) void prep_b_k(const float* __restrict__ Wm, f16* __restrict__ Bt) {
  int idx = blockIdx.x*256 + threadIdx.x;   // 0..409599
  int lane = idx & 63;
  int t    = idx >> 6;
  int kstep = t % 40, ntile = t / 40;
  int s = ntile / 5, g = ntile % 5;
  int n = g*512 + s*16 + (lane & 15);
  int k = kstep*32 + (lane >> 4)*8;
  f16x8 vh, vl;
#pragma unroll
  for (int u = 0; u < 8; ++u) {
    float w = Wm[(long)(k+u)*2560 + n] * 64.0f;
    f16 hi = (f16)w;
    vh[u] = hi;
    vl[u] = (f16)(w - (float)hi);
  }
  ((f16x8*)Bt)[(long)idx*2]     = vh;
  ((f16x8*)Bt)[(long)idx*2 + 1] = vl;
}

__device__ __forceinline__ float sigf(float x) { return 1.0f/(1.0f + __expf(-x)); }
__device__ __forceinline__ float tanh_fast(float x) {
  float e = __expf(-2.0f*fabsf(x));
  float t = (1.0f - e)/(1.0f + e);
  return x >= 0.0f ? t : -t;
}

// load next k-step's A (4 m-tiles x hi/lo) and B (5 gates x hi/lo) into named slot regs
#define PREFETCH(PF, AH, AL, BH, BL)                                          \
  { const int pf_ = (PF);                                                     \
    if (pf_ < 40) {                                                           \
      const f16 *q0h, *q0l, *q1h, *q1l; int str_, kl_;                        \
      if (pf_ < 8)       { str_=256; kl_=pf_*32;      q0h=pxh0; q0l=pxl0; q1h=pxh1; q1l=pxl1; } \
      else if (pf_ < 24) { str_=512; kl_=(pf_-8)*32;  q0h=puh0; q0l=pul0; q1h=puh1; q1l=pul1; } \
      else               { str_=512; kl_=(pf_-24)*32; q0h=plh0; q0l=pll0; q1h=plh1; q1l=pll1; } \
      const int oA_ = kl_ + l4*8;                                             \
      const int rA_ = l15*str_, rB_ = (16+l15)*str_;                          \
      AH[0] = *(const f16x8*)(q0h + rA_ + oA_);                               \
      AL[0] = *(const f16x8*)(q0l + rA_ + oA_);                               \
      AH[1] = *(const f16x8*)(q0h + rB_ + oA_);                               \
      AL[1] = *(const f16x8*)(q0l + rB_ + oA_);                               \
      AH[2] = *(const f16x8*)(q1h + rA_ + oA_);                               \
      AL[2] = *(const f16x8*)(q1l + rA_ + oA_);                               \
      AH[3] = *(const f16x8*)(q1h + rB_ + oA_);                               \
      AL[3] = *(const f16x8*)(q1l + rB_ + oA_);                               \
      _Pragma("unroll")                                                       \
      for (int g = 0; g < 5; ++g) {                                           \
        const long b2_ = ((long)bfbase + g*2560 + pf_*64)*2;                  \
        BH[g] = Bf[b2_]; BL[g] = Bf[b2_+1];                                   \
      } } }

#define MFMAS(AH, AL, BH, BL)                                                 \
  _Pragma("unroll")                                                           \
  for (int mt = 0; mt < 4; ++mt) {                                            \
    _Pragma("unroll")                                                         \
    for (int g = 0; g < 5; ++g) {                                             \
      acc[mt][g] = __builtin_amdgcn_mfma_f32_16x16x32_f16(AH[mt], BH[g], acc[mt][g], 0,0,0); \
      acc[mt][g] = __builtin_amdgcn_mfma_f32_16x16x32_f16(AL[mt], BH[g], acc[mt][g], 0,0,0); \
      acc[mt][g] = __builtin_amdgcn_mfma_f32_16x16x32_f16(AH[mt], BL[g], acc[mt][g], 0,0,0); \
    } }

#define EPILOG(MT0, IV, JV)                                                   \
  { const long wb_ = ((long)((d&1)*32 + (IV)))*16384;                         \
    const long ru_ = ((long)(rprev + (IV)-1))*16384;                          \
    const long rl_ = ((long)(rprev + (IV)))*16384;                            \
    _Pragma("unroll")                                                         \
    for (int m = 0; m < 2; ++m) {                                             \
      _Pragma("unroll")                                                       \
      for (int v = 0; v < 4; ++v) {                                           \
        const int brow = m*16 + l4*4 + v;                                     \
        const int off = brow*512 + r0 + l15;                                  \
        float cu = ((IV) > 0) ? cr[ru_ + off] : 0.0f;                         \
        float cl = ((JV) > 0) ? cr[rl_ + off] : 0.0f;                         \
        float zi  = acc[MT0+m][0][v]*SCL + bia[0];                            \
        float zj  = acc[MT0+m][1][v]*SCL + bia[1];                            \
        float zf1 = acc[MT0+m][2][v]*SCL + bia[2];                            \
        float zf2 = acc[MT0+m][3][v]*SCL + bia[3];                            \
        float zo  = acc[MT0+m][4][v]*SCL + bia[4];                            \
        float nc = cu*sigf(zf1) + cl*sigf(zf2) + sigf(zi)*tanh_fast(zj);      \
        float nh = tanh_fast(nc)*sigf(zo);                                    \
        cr[wb_ + off] = nc;                                                   \
        float nhs = nh * 16.0f;                                               \
        f16 hh_ = (f16)nhs;                                                   \
        hr[wb_ + off] = hh_;                                                  \
        hr[HR_PLANE + wb_ + off] = (f16)(nhs - (float)hh_);                   \
        __builtin_nontemporal_store(nh, out + (((long)brow*32 + (IV))*32 + (JV))*512 + r0 + l15); \
      } } }

// ---------------- main persistent wavefront kernel ----------------
// 128 WGs x 256 thr. wid: xcd=wid&7, q=wid>>3, subslice=q&3, group=q>>2 (0..3).
// slice s = subslice*8+xcd (B pinned to XCD L2). Wave handles 2 cells: L = group*8+wave*2+{0,1}.
__global__ __launch_bounds__(256, 1) void mdlstm_wave_k(
    const f16* __restrict__ Bt, const f16* __restrict__ xg,
    f16* __restrict__ hr, float* __restrict__ cr,
    const float* __restrict__ bias, const f16* __restrict__ zb,
    float* __restrict__ out, int* __restrict__ flags)
{
  const int wid = blockIdx.x;
  const int xcd = wid & 7, qq = wid >> 3;
  const int subslice = qq & 3, group = qq >> 2;
  const int s = subslice*8 + xcd, r0 = s*16;
  const int tid = threadIdx.x, wave = tid >> 6, lane = tid & 63;
  const int l15 = lane & 15, l4 = lane >> 4;
  const f16x8* __restrict__ Bf = (const f16x8*)Bt;
  const int bfbase = s*12800 + lane;      // frag idx = bfbase + g*2560 + ks*64

  float bia[5];
#pragma unroll
  for (int g = 0; g < 5; ++g) bia[g] = bias[g*512 + r0 + l15];

  for (int d = 0; d < 63; ++d) {
    if (d > 0) {
      if (tid == 0) {
        while (__hip_atomic_load(&flags[d-1], __ATOMIC_ACQUIRE, __HIP_MEMORY_SCOPE_AGENT) < NWG)
          __builtin_amdgcn_s_sleep(2);
      }
      __syncthreads();
    }
    const int ncell = (d < 32) ? (d + 1) : (63 - d);
    const int i0    = (d < 32) ? 0 : (d - 31);
    const int Lb    = group*8 + wave*2;
    const int rprev = ((d-1)&1)*32;

    if (Lb < ncell) {
      const int i_0 = i0 + Lb,     j_0 = d - i_0;
      const int v1  = (Lb + 1 < ncell);
      const int i_1 = i0 + Lb + 1, j_1 = d - i_1;
      const long cid0 = (long)i_0*32 + j_0;
      const long cid1 = (long)i_1*32 + j_1;

      const f16 *pxh0 = xg + cid0*8192,            *pxl0 = xg + XG_PLANE + cid0*8192;
      const f16 *pxh1 = v1 ? (xg + cid1*8192) : zb;
      const f16 *pxl1 = v1 ? (xg + XG_PLANE + cid1*8192) : zb;
      const f16 *puh0 = (i_0>0) ? (hr + ((long)(rprev + i_0-1))*16384) : zb;
      const f16 *pul0 = (i_0>0) ? (hr + HR_PLANE + ((long)(rprev + i_0-1))*16384) : zb;
      const f16 *plh0 = (j_0>0) ? (hr + ((long)(rprev + i_0))*16384) : zb;
      const f16 *pll0 = (j_0>0) ? (hr + HR_PLANE + ((long)(rprev + i_0))*16384) : zb;
      const f16 *puh1 = v1 ? (hr + ((long)(rprev + i_1-1))*16384) : zb;   // i_1 >= 1 always
      const f16 *pul1 = v1 ? (hr + HR_PLANE + ((long)(rprev + i_1-1))*16384) : zb;
      const f16 *plh1 = (v1 && j_1>0) ? (hr + ((long)(rprev + i_1))*16384) : zb;
      const f16 *pll1 = (v1 && j_1>0) ? (hr + HR_PLANE + ((long)(rprev + i_1))*16384) : zb;

      f32x4 acc[4][5];
#pragma unroll
      for (int mt = 0; mt < 4; ++mt)
#pragma unroll
        for (int g = 0; g < 5; ++g) acc[mt][g] = (f32x4){0.f,0.f,0.f,0.f};

      f16x8 Ah0[4], Al0[4], Ah1[4], Al1[4];
      f16x8 Bh0[5], Bl0[5], Bh1[5], Bl1[5];
      PREFETCH(0, Ah0, Al0, Bh0, Bl0);
#pragma unroll 1
      for (int ks = 0; ks < 40; ks += 2) {
        PREFETCH(ks+1, Ah1, Al1, Bh1, Bl1);
        MFMAS(Ah0, Al0, Bh0, Bl0);
        PREFETCH(ks+2, Ah0, Al0, Bh0, Bl0);
        MFMAS(Ah1, Al1, Bh1, Bl1);
      }

      EPILOG(0, i_0, j_0);
      if (v1) { EPILOG(2, i_1, j_1); }
    }

    __threadfence();
    __syncthreads();
    if (tid == 0) atomicAdd(&flags[d], 1);
  }
}

extern "C" void kernel_launch(void* const* d_in, const int* in_sizes, int n_in,
                              void* d_out, int out_size, void* d_ws, size_t ws_size,
                              hipStream_t stream) {
  const float* x  = (const float*)d_in[0];   // [32,16,128,128]
  const float* Wm = (const float*)d_in[1];   // [1280,2560]
  const float* bs = (const float*)d_in[2];   // [2560]
  float* out = (float*)d_out;                // [32,32,32,512]
  char* ws = (char*)d_ws;                    // needs ~52.7 MiB

  int*   flags = (int*)(ws + FLAGS_OFF);
  f16*   zb    = (f16*)(ws + ZERO_OFF);
  f16*   Bt    = (f16*)(ws + BT_OFF);
  f16*   xgb   = (f16*)(ws + XG_OFF);
  f16*   hrb   = (f16*)(ws + HR_OFF);
  float* crb   = (float*)(ws + CR_OFF);

  hipMemsetAsync(ws, 0, BT_OFF, stream);     // flags + zero block
  gather_xg_k<<<32768, 256, 0, stream>>>(x, xgb);
  prep_b_k<<<1600, 256, 0, stream>>>(Wm, Bt);
  mdlstm_wave_k<<<NWG, 256, 0, stream>>>(Bt, xgb, hrb, crb, bs, zb, out, flags);
}

// Round 3
// 5015.350 us; speedup vs baseline: 1.1485x; 1.1485x over previous
//
#include <hip/hip_runtime.h>

// 2D-MDLSTM wavefront kernel for MI355X (gfx950), full hi/lo f16-split precision.
// z = [x(256) | h_up(512) | h_left(512)] @ W(1280x2560) + b, gates i,j,f1,f2,o.
// Split: every operand O = Oh + Ol (f16 pair); z-term = AhBh + AlBh + AhBl (fp32 acc).
// Scaling: A-planes *16, B-planes *64; z = acc/1024 + b.
// Coherence protocol (round 3): B/xg/bias = normal loads (L2-resident, never invalidated);
// h/c rings = system-scope (sc0 sc1) loads/stores via atomics/asm (L3-served, cross-XCD safe);
// flags = relaxed agent atomics. No __threadfence, no acquire (no buffer_inv / wbl2).

typedef _Float16 f16;
typedef f16   f16x8 __attribute__((ext_vector_type(8)));
typedef float f32x4 __attribute__((ext_vector_type(4)));
typedef unsigned long long ull;
struct U2 { ull a, b; };

#define NWG 128
#define SCL (1.0f/1024.0f)

// workspace layout (bytes); total ~52.7 MiB
#define FLAGS_OFF 0L
#define ZERO_OFF  4096L                 // zeros through BT_OFF (memset prefix)
#define BT_OFF    131072L
#define BT_BYTES  13107200L             // 409600 frags * 16 f16 * 2B (hi/lo interleaved)
#define XG_OFF    (BT_OFF + BT_BYTES)
#define XG_PLANE  8388608L              // elems per plane (1024*32*256)
#define XG_BYTES  (XG_PLANE*4L)
#define HR_OFF    (XG_OFF + XG_BYTES)
#define HR_PLANE  1048576L              // elems per plane (2*32*16384)
#define HR_BYTES  (HR_PLANE*4L)
#define CR_OFF    (HR_OFF + HR_BYTES)
#define CR_BYTES  (HR_PLANE*4L)

// ---------------- prep: gather x -> xg f16 hi/lo planes [cell][b][f] ----------------
__global__ __launch_bounds__(256) void gather_xg_k(const float* __restrict__ x, f16* __restrict__ xg) {
  int cb = blockIdx.x;                  // cell*32 + b
  int f  = threadIdx.x;
  int cell = cb >> 5, b = cb & 31;
  int hh = cell >> 5, ww = cell & 31;
  int c  = f & 15, fo = f >> 4;
  int xd = hh*4 + (ww >> 3);
  int yd = (ww & 7)*16 + fo;
  float v = x[(((long)b*16 + c)*128 + xd)*128 + yd] * 16.0f;
  f16 hi = (f16)v;
  f16 lo = (f16)(v - (float)hi);
  long o = (long)cb*256 + f;
  xg[o] = hi;
  xg[XG_PLANE + o] = lo;
}

// ---------------- prep: W -> f16 hi/lo frag pairs, column-permuted ----------------
__global__ __launch_bounds__(256) void prep_b_k(const float* __restrict__ Wm, f16* __restrict__ Bt) {
  int idx = blockIdx.x*256 + threadIdx.x;   // 0..409599
  int lane = idx & 63;
  int t    = idx >> 6;
  int kstep = t % 40, ntile = t / 40;
  int s = ntile / 5, g = ntile % 5;
  int n = g*512 + s*16 + (lane & 15);
  int k = kstep*32 + (lane >> 4)*8;
  f16x8 vh, vl;
#pragma unroll
  for (int u = 0; u < 8; ++u) {
    float w = Wm[(long)(k+u)*2560 + n] * 64.0f;
    f16 hi = (f16)w;
    vh[u] = hi;
    vl[u] = (f16)(w - (float)hi);
  }
  ((f16x8*)Bt)[(long)idx*2]     = vh;
  ((f16x8*)Bt)[(long)idx*2 + 1] = vl;
}

__device__ __forceinline__ float sigf(float x) { return 1.0f/(1.0f + __expf(-x)); }
__device__ __forceinline__ float tanh_fast(float x) {
  float e = __expf(-2.0f*fabsf(x));
  float t = (1.0f - e)/(1.0f + e);
  return x >= 0.0f ? t : -t;
}

// ---- system-scope (cross-XCD coherent, L2-bypassing, L3-served) accessors ----
__device__ __forceinline__ f16x8 ld_sys16(const f16* p) {
  ull lo = __hip_atomic_load((const ull*)p,     __ATOMIC_RELAXED, __HIP_MEMORY_SCOPE_SYSTEM);
  ull hi = __hip_atomic_load((const ull*)p + 1, __ATOMIC_RELAXED, __HIP_MEMORY_SCOPE_SYSTEM);
  U2 u{lo, hi};
  return __builtin_bit_cast(f16x8, u);
}
__device__ __forceinline__ float ld_sys_f32(const float* p) {
  unsigned v = __hip_atomic_load((const unsigned*)p, __ATOMIC_RELAXED, __HIP_MEMORY_SCOPE_SYSTEM);
  return __builtin_bit_cast(float, v);
}
__device__ __forceinline__ void st_sys_f32(float* p, float v) {
  __hip_atomic_store((unsigned*)p, __builtin_bit_cast(unsigned, v), __ATOMIC_RELAXED, __HIP_MEMORY_SCOPE_SYSTEM);
}
__device__ __forceinline__ void st_sys_f16(f16* p, f16 v) {
  unsigned short b = __builtin_bit_cast(unsigned short, v);
  unsigned v32 = b;
  asm volatile("global_store_short %0, %1, off sc0 sc1" :: "v"(p), "v"(v32) : "memory");
}

// A prefetch: kstep pf -> 4 m-tile frags hi/lo. pf<8: xg via NORMAL loads (L2-warm);
// pf>=8: h ring via system-scope loads (L3).
#define PREFA(PF, AH, AL)                                                     \
  { const int pf_ = (PF);                                                     \
    if (pf_ < 8) {                                                            \
      const int oA_ = pf_*32 + l4*8;                                          \
      const int rA_ = l15*256, rB_ = (16+l15)*256;                            \
      AH[0] = *(const f16x8*)(pxh0 + rA_ + oA_);                              \
      AL[0] = *(const f16x8*)(pxl0 + rA_ + oA_);                              \
      AH[1] = *(const f16x8*)(pxh0 + rB_ + oA_);                              \
      AL[1] = *(const f16x8*)(pxl0 + rB_ + oA_);                              \
      AH[2] = *(const f16x8*)(pxh1 + rA_ + oA_);                              \
      AL[2] = *(const f16x8*)(pxl1 + rA_ + oA_);                              \
      AH[3] = *(const f16x8*)(pxh1 + rB_ + oA_);                              \
      AL[3] = *(const f16x8*)(pxl1 + rB_ + oA_);                              \
    } else {                                                                  \
      const f16 *qh0, *ql0, *qh1, *ql1; int kl_;                              \
      if (pf_ < 24) { kl_=(pf_-8)*32;  qh0=puh0; ql0=pul0; qh1=puh1; ql1=pul1; } \
      else          { kl_=(pf_-24)*32; qh0=plh0; ql0=pll0; qh1=plh1; ql1=pll1; } \
      const int oA_ = kl_ + l4*8;                                             \
      const int rA_ = l15*512, rB_ = (16+l15)*512;                            \
      AH[0] = ld_sys16(qh0 + rA_ + oA_);                                      \
      AL[0] = ld_sys16(ql0 + rA_ + oA_);                                      \
      AH[1] = ld_sys16(qh0 + rB_ + oA_);                                      \
      AL[1] = ld_sys16(ql0 + rB_ + oA_);                                      \
      AH[2] = ld_sys16(qh1 + rA_ + oA_);                                      \
      AL[2] = ld_sys16(ql1 + rA_ + oA_);                                      \
      AH[3] = ld_sys16(qh1 + rB_ + oA_);                                      \
      AL[3] = ld_sys16(ql1 + rB_ + oA_);                                      \
    } }

#define PREFB(PF, BH, BL)                                                     \
  { const int pf_ = (PF);                                                     \
    _Pragma("unroll")                                                         \
    for (int g = 0; g < 5; ++g) {                                             \
      const long b2_ = ((long)bfbase + g*2560 + pf_*64)*2;                    \
      BH[g] = Bf[b2_]; BL[g] = Bf[b2_+1];                                     \
    } }

#define MFMAS(AH, AL, BH, BL)                                                 \
  _Pragma("unroll")                                                           \
  for (int mt = 0; mt < 4; ++mt) {                                            \
    _Pragma("unroll")                                                         \
    for (int g = 0; g < 5; ++g) {                                             \
      acc[mt][g] = __builtin_amdgcn_mfma_f32_16x16x32_f16(AH[mt], BH[g], acc[mt][g], 0,0,0); \
      acc[mt][g] = __builtin_amdgcn_mfma_f32_16x16x32_f16(AL[mt], BH[g], acc[mt][g], 0,0,0); \
      acc[mt][g] = __builtin_amdgcn_mfma_f32_16x16x32_f16(AH[mt], BL[g], acc[mt][g], 0,0,0); \
    } }

#define STAGE(KS, AH, AL, BH, BL)                                             \
  { const int ks_ = (KS);                                                     \
    if (ks_ < 40) {                                                           \
      MFMAS(AH, AL, BH, BL);                                                  \
      if (ks_ + 3 < 40) PREFA(ks_ + 3, AH, AL);                               \
      if (ks_ + 2 < 40) PREFB(ks_ + 2, BH, BL);                               \
    } }

// CP = cell index within wave (0/1), selects acc pair MT0 = CP*2 and preloaded c regs
#define EPILOG(CP, IV, JV)                                                    \
  { const long wb_ = ((long)((d&1)*32 + (IV)))*16384;                         \
    _Pragma("unroll")                                                         \
    for (int m = 0; m < 2; ++m) {                                             \
      _Pragma("unroll")                                                       \
      for (int v = 0; v < 4; ++v) {                                           \
        const int brow = m*16 + l4*4 + v;                                     \
        const int off = brow*512 + r0 + l15;                                  \
        float cu = cu_r[CP][m][v];                                            \
        float cl = cl_r[CP][m][v];                                            \
        float zi  = acc[CP*2+m][0][v]*SCL + bia[0];                           \
        float zj  = acc[CP*2+m][1][v]*SCL + bia[1];                           \
        float zf1 = acc[CP*2+m][2][v]*SCL + bia[2];                           \
        float zf2 = acc[CP*2+m][3][v]*SCL + bia[3];                           \
        float zo  = acc[CP*2+m][4][v]*SCL + bia[4];                           \
        float nc = cu*sigf(zf1) + cl*sigf(zf2) + sigf(zi)*tanh_fast(zj);      \
        float nh = tanh_fast(nc)*sigf(zo);                                    \
        st_sys_f32(cr + wb_ + off, nc);                                       \
        float nhs = nh * 16.0f;                                               \
        f16 hh_ = (f16)nhs;                                                   \
        st_sys_f16(hr + wb_ + off, hh_);                                      \
        st_sys_f16(hr + HR_PLANE + wb_ + off, (f16)(nhs - (float)hh_));       \
        __builtin_nontemporal_store(nh, out + (((long)brow*32 + (IV))*32 + (JV))*512 + r0 + l15); \
      } } }

// ---------------- main persistent wavefront kernel ----------------
// 128 WGs x 256 thr. wid: xcd=wid&7, q=wid>>3, subslice=q&3, group=q>>2 (0..3).
// slice s = subslice*8+xcd (B pinned to XCD L2). Wave handles 2 cells: L = group*8+wave*2+{0,1}.
__global__ __launch_bounds__(256, 1) void mdlstm_wave_k(
    const f16* __restrict__ Bt, const f16* __restrict__ xg,
    f16* __restrict__ hr, float* __restrict__ cr,
    const float* __restrict__ bias, const f16* __restrict__ zb,
    float* __restrict__ out, int* __restrict__ flags)
{
  const int wid = blockIdx.x;
  const int xcd = wid & 7, qq = wid >> 3;
  const int subslice = qq & 3, group = qq >> 2;
  const int s = subslice*8 + xcd, r0 = s*16;
  const int tid = threadIdx.x, wave = tid >> 6, lane = tid & 63;
  const int l15 = lane & 15, l4 = lane >> 4;
  const f16x8* __restrict__ Bf = (const f16x8*)Bt;
  const int bfbase = s*12800 + lane;      // frag idx = bfbase + g*2560 + ks*64

  float bia[5];
#pragma unroll
  for (int g = 0; g < 5; ++g) bia[g] = bias[g*512 + r0 + l15];

  for (int d = 0; d < 63; ++d) {
    if (d > 0) {
      if (tid == 0) {
        while (__hip_atomic_load(&flags[d-1], __ATOMIC_RELAXED, __HIP_MEMORY_SCOPE_AGENT) < NWG)
          __builtin_amdgcn_s_sleep(1);
      }
      __syncthreads();
    }
    const int ncell = (d < 32) ? (d + 1) : (63 - d);
    const int i0    = (d < 32) ? 0 : (d - 31);
    const int Lb    = group*8 + wave*2;
    const int rprev = ((d-1)&1)*32;

    if (Lb < ncell) {
      const int i_0 = i0 + Lb,     j_0 = d - i_0;
      const int v1  = (Lb + 1 < ncell);
      const int i_1 = i0 + Lb + 1, j_1 = d - i_1;
      const long cid0 = (long)i_0*32 + j_0;
      const long cid1 = (long)i_1*32 + j_1;

      const f16 *pxh0 = xg + cid0*8192,            *pxl0 = xg + XG_PLANE + cid0*8192;
      const f16 *pxh1 = v1 ? (xg + cid1*8192) : zb;
      const f16 *pxl1 = v1 ? (xg + XG_PLANE + cid1*8192) : zb;
      const f16 *puh0 = (i_0>0) ? (hr + ((long)(rprev + i_0-1))*16384) : zb;
      const f16 *pul0 = (i_0>0) ? (hr + HR_PLANE + ((long)(rprev + i_0-1))*16384) : zb;
      const f16 *plh0 = (j_0>0) ? (hr + ((long)(rprev + i_0))*16384) : zb;
      const f16 *pll0 = (j_0>0) ? (hr + HR_PLANE + ((long)(rprev + i_0))*16384) : zb;
      const f16 *puh1 = v1 ? (hr + ((long)(rprev + i_1-1))*16384) : zb;   // i_1 >= 1 always
      const f16 *pul1 = v1 ? (hr + HR_PLANE + ((long)(rprev + i_1-1))*16384) : zb;
      const f16 *plh1 = (v1 && j_1>0) ? (hr + ((long)(rprev + i_1))*16384) : zb;
      const f16 *pll1 = (v1 && j_1>0) ? (hr + HR_PLANE + ((long)(rprev + i_1))*16384) : zb;

      // ---- hoisted c-ring preloads (system scope, latency hidden under K-loop) ----
      float cu_r[2][2][4], cl_r[2][2][4];
#pragma unroll
      for (int m = 0; m < 2; ++m)
#pragma unroll
        for (int v = 0; v < 4; ++v) {
          const int off = (m*16 + l4*4 + v)*512 + r0 + l15;
          const long ru0 = ((long)(rprev + i_0-1))*16384;
          const long rl0 = ((long)(rprev + i_0))*16384;
          const long ru1 = ((long)(rprev + i_1-1))*16384;
          const long rl1 = ((long)(rprev + i_1))*16384;
          cu_r[0][m][v] = (i_0>0)        ? ld_sys_f32(cr + ru0 + off) : 0.0f;
          cl_r[0][m][v] = (j_0>0)        ? ld_sys_f32(cr + rl0 + off) : 0.0f;
          cu_r[1][m][v] = v1             ? ld_sys_f32(cr + ru1 + off) : 0.0f;
          cl_r[1][m][v] = (v1 && j_1>0)  ? ld_sys_f32(cr + rl1 + off) : 0.0f;
        }

      f32x4 acc[4][5];
#pragma unroll
      for (int mt = 0; mt < 4; ++mt)
#pragma unroll
        for (int g = 0; g < 5; ++g) acc[mt][g] = (f32x4){0.f,0.f,0.f,0.f};

      f16x8 A0h[4], A0l[4], A1h[4], A1l[4], A2h[4], A2l[4];
      f16x8 B0h[5], B0l[5], B1h[5], B1l[5];
      PREFA(0, A0h, A0l); PREFA(1, A1h, A1l); PREFA(2, A2h, A2l);
      PREFB(0, B0h, B0l); PREFB(1, B1h, B1l);
#pragma unroll 1
      for (int ks = 0; ks < 42; ks += 6) {
        STAGE(ks+0, A0h, A0l, B0h, B0l);
        STAGE(ks+1, A1h, A1l, B1h, B1l);
        STAGE(ks+2, A2h, A2l, B0h, B0l);
        STAGE(ks+3, A0h, A0l, B1h, B1l);
        STAGE(ks+4, A1h, A1l, B0h, B0l);
        STAGE(ks+5, A2h, A2l, B1h, B1l);
      }

      EPILOG(0, i_0, j_0);
      if (v1) { EPILOG(1, i_1, j_1); }
    }

    __syncthreads();   // drains each wave's vmcnt (incl. system-scope stores)
    if (tid == 0) __hip_atomic_fetch_add(&flags[d], 1, __ATOMIC_RELAXED, __HIP_MEMORY_SCOPE_AGENT);
  }
}

extern "C" void kernel_launch(void* const* d_in, const int* in_sizes, int n_in,
                              void* d_out, int out_size, void* d_ws, size_t ws_size,
                              hipStream_t stream) {
  const float* x  = (const float*)d_in[0];   // [32,16,128,128]
  const float* Wm = (const float*)d_in[1];   // [1280,2560]
  const float* bs = (const float*)d_in[2];   // [2560]
  float* out = (float*)d_out;                // [32,32,32,512]
  char* ws = (char*)d_ws;                    // needs ~52.7 MiB

  int*   flags = (int*)(ws + FLAGS_OFF);
  f16*   zb    = (f16*)(ws + ZERO_OFF);
  f16*   Bt    = (f16*)(ws + BT_OFF);
  f16*   xgb   = (f16*)(ws + XG_OFF);
  f16*   hrb   = (f16*)(ws + HR_OFF);
  float* crb   = (float*)(ws + CR_OFF);

  hipMemsetAsync(ws, 0, BT_OFF, stream);     // flags + zero block
  gather_xg_k<<<32768, 256, 0, stream>>>(x, xgb);
  prep_b_k<<<1600, 256, 0, stream>>>(Wm, Bt);
  mdlstm_wave_k<<<NWG, 256, 0, stream>>>(Bt, xgb, hrb, crb, bs, zb, out, flags);
}

// Round 4
// 3057.506 us; speedup vs baseline: 1.8839x; 1.6403x over previous
//
#include <hip/hip_runtime.h>

// 2D-MDLSTM wavefront kernel for MI355X (gfx950), full hi/lo f16-split precision.
// z = [x(256) | h_up(512) | h_left(512)] @ W(1280x2560) + b, gates i,j,f1,f2,o.
// Split: every operand O = Oh + Ol (f16 pair); z-term = AhBh + AlBh + AhBl (fp32 acc).
// Scaling: A-planes *16, B-planes *64; z = acc/1024 + b.
// Round 4: K-split x4 across the WG's 4 waves (wave = 10 ksteps), LDS partial-sum
// reduction, 768 WGs (3/CU => 3 waves/SIMD TLP). Ring coherence: stores sc0sc1
// (write-through to IF), loads nontemporal (no L2 allocate => always IF-fresh,
// compiler-pipelined). Two-level flag barrier (6 groups x 128).

typedef _Float16 f16;
typedef f16   f16x8 __attribute__((ext_vector_type(8)));
typedef float f32x4 __attribute__((ext_vector_type(4)));

#define SCL (1.0f/1024.0f)

// workspace layout (bytes); total ~52.7 MiB
#define FLAGS_OFF  0L
#define FLAGS2_OFF 4096L                // (d*6+grp)*16 ints, 64B-padded counters
#define ZERO_OFF   40960L               // 32 KB zero block
#define BT_OFF     131072L
#define BT_BYTES   13107200L            // 409600 frags * 16 f16 * 2B (hi/lo interleaved)
#define XG_OFF     (BT_OFF + BT_BYTES)
#define XG_PLANE   8388608L             // elems per plane (1024*32*256)
#define XG_BYTES   (XG_PLANE*4L)
#define HR_OFF     (XG_OFF + XG_BYTES)
#define HR_PLANE   1048576L             // elems per plane (2*32*16384)
#define HR_BYTES   (HR_PLANE*4L)
#define CR_OFF     (HR_OFF + HR_BYTES)
#define CR_BYTES   (HR_PLANE*4L)

// ---------------- prep: gather x -> xg f16 hi/lo planes [cell][b][f] ----------------
__global__ __launch_bounds__(256) void gather_xg_k(const float* __restrict__ x, f16* __restrict__ xg) {
  int cb = blockIdx.x;                  // cell*32 + b
  int f  = threadIdx.x;
  int cell = cb >> 5, b = cb & 31;
  int hh = cell >> 5, ww = cell & 31;
  int c  = f & 15, fo = f >> 4;
  int xd = hh*4 + (ww >> 3);
  int yd = (ww & 7)*16 + fo;
  float v = x[(((long)b*16 + c)*128 + xd)*128 + yd] * 16.0f;
  f16 hi = (f16)v;
  f16 lo = (f16)(v - (float)hi);
  long o = (long)cb*256 + f;
  xg[o] = hi;
  xg[XG_PLANE + o] = lo;
}

// ---------------- prep: W -> f16 hi/lo frag pairs, column-permuted ----------------
__global__ __launch_bounds__(256) void prep_b_k(const float* __restrict__ Wm, f16* __restrict__ Bt) {
  int idx = blockIdx.x*256 + threadIdx.x;   // 0..409599
  int lane = idx & 63;
  int t    = idx >> 6;
  int kstep = t % 40, ntile = t / 40;
  int s = ntile / 5, g = ntile % 5;
  int n = g*512 + s*16 + (lane & 15);
  int k = kstep*32 + (lane >> 4)*8;
  f16x8 vh, vl;
#pragma unroll
  for (int u = 0; u < 8; ++u) {
    float w = Wm[(long)(k+u)*2560 + n] * 64.0f;
    f16 hi = (f16)w;
    vh[u] = hi;
    vl[u] = (f16)(w - (float)hi);
  }
  ((f16x8*)Bt)[(long)idx*2]     = vh;
  ((f16x8*)Bt)[(long)idx*2 + 1] = vl;
}

__device__ __forceinline__ float sigf(float x) { return 1.0f/(1.0f + __expf(-x)); }
__device__ __forceinline__ float tanh_fast(float x) {
  float e = __expf(-2.0f*fabsf(x));
  float t = (1.0f - e)/(1.0f + e);
  return x >= 0.0f ? t : -t;
}

// nontemporal loads: no L2 allocate -> served from IF (fresh), compiler-pipelined
__device__ __forceinline__ f16x8 ld_nt(const f16* p) {
  return __builtin_nontemporal_load((const f16x8*)p);
}
__device__ __forceinline__ float ld_ntf(const float* p) {
  return __builtin_nontemporal_load(p);
}
// system-scope write-through stores (fire-and-forget; drained by vmcnt(0) at diag end)
__device__ __forceinline__ void st_sc_f32(float* p, float v) {
  asm volatile("global_store_dword %0, %1, off sc0 sc1" :: "v"(p), "v"(v) : "memory");
}
__device__ __forceinline__ void st_sc_f16(f16* p, f16 v) {
  unsigned v32 = (unsigned)__builtin_bit_cast(unsigned short, v);
  asm volatile("global_store_short %0, %1, off sc0 sc1" :: "v"(p), "v"(v32) : "memory");
}

// A prefetch for global kstep PF: 2 m-tiles x hi/lo. x-region: normal cached loads;
// h-ring: nontemporal.
#define PREFA(PF, A0H, A0L, A1H, A1L)                                         \
  { const int pfa_ = (PF);                                                    \
    if (pfa_ < 8) {                                                           \
      const int o_ = pfa_*32 + l4*8;                                          \
      A0H = *(const f16x8*)(pxh + l15*256 + o_);                              \
      A0L = *(const f16x8*)(pxl + l15*256 + o_);                              \
      A1H = *(const f16x8*)(pxh + (16+l15)*256 + o_);                         \
      A1L = *(const f16x8*)(pxl + (16+l15)*256 + o_);                         \
    } else {                                                                  \
      const f16 *qh_, *ql_; int kl_;                                          \
      if (pfa_ < 24) { kl_ = (pfa_-8)*32;  qh_ = puh; ql_ = pul; }            \
      else           { kl_ = (pfa_-24)*32; qh_ = plh; ql_ = pll; }            \
      const int o_ = kl_ + l4*8;                                              \
      A0H = ld_nt(qh_ + l15*512 + o_);                                        \
      A0L = ld_nt(ql_ + l15*512 + o_);                                        \
      A1H = ld_nt(qh_ + (16+l15)*512 + o_);                                   \
      A1L = ld_nt(ql_ + (16+l15)*512 + o_);                                   \
    } }

#define PREFB(PF)                                                             \
  { const int pfb_ = (PF);                                                    \
    _Pragma("unroll")                                                         \
    for (int g = 0; g < 5; ++g) {                                             \
      const long b2_ = ((long)bfbase + g*2560 + pfb_*64)*2;                   \
      Bh[g] = Bf[b2_]; Bl[g] = Bf[b2_+1];                                     \
    } }

#define MFMAS(A0H, A0L, A1H, A1L)                                             \
  _Pragma("unroll")                                                           \
  for (int g = 0; g < 5; ++g) {                                               \
    acc[0][g] = __builtin_amdgcn_mfma_f32_16x16x32_f16(A0H, Bh[g], acc[0][g], 0,0,0); \
    acc[0][g] = __builtin_amdgcn_mfma_f32_16x16x32_f16(A0L, Bh[g], acc[0][g], 0,0,0); \
    acc[0][g] = __builtin_amdgcn_mfma_f32_16x16x32_f16(A0H, Bl[g], acc[0][g], 0,0,0); \
    acc[1][g] = __builtin_amdgcn_mfma_f32_16x16x32_f16(A1H, Bh[g], acc[1][g], 0,0,0); \
    acc[1][g] = __builtin_amdgcn_mfma_f32_16x16x32_f16(A1L, Bh[g], acc[1][g], 0,0,0); \
    acc[1][g] = __builtin_amdgcn_mfma_f32_16x16x32_f16(A1H, Bl[g], acc[1][g], 0,0,0); \
  }

// ---------------- main persistent wavefront kernel ----------------
// 768 WGs x 256 thr (3 WGs/CU => 3 waves/SIMD). wid: xcd=wid&7, u=wid>>3 (0..95),
// subslice=u&3 -> slice s=subslice*8+xcd (B pinned to XCD L2), cellgroup=u>>2 (0..23).
// WG-task = (cell, slice); 4 waves = 4 K-chunks of 320 (10 ksteps each);
// LDS reduce partials; waves 0/1 epilogue (m-halves). Cells L = cellgroup (+24).
__global__ __launch_bounds__(256, 3) void mdlstm_wave_k(
    const f16* __restrict__ Bt, const f16* __restrict__ xg,
    f16* __restrict__ hr, float* __restrict__ cr,
    const float* __restrict__ bias, const f16* __restrict__ zb,
    float* __restrict__ out, int* __restrict__ flags, int* __restrict__ flags2)
{
  const int wid = blockIdx.x;
  const int xcd = wid & 7, u = wid >> 3;
  const int subslice = u & 3, cellgroup = u >> 2;
  const int s = subslice*8 + xcd, r0 = s*16;
  const int grp6 = wid >> 7;                 // 0..5
  const bool leader = (wid & 127) == 0;
  const int tid = threadIdx.x, wave = tid >> 6, lane = tid & 63;
  const int l15 = lane & 15, l4 = lane >> 4;
  const f16x8* __restrict__ Bf = (const f16x8*)Bt;
  const int bfbase = s*12800 + lane;         // frag idx = bfbase + g*2560 + ks*64
  const int kb = wave*10;                    // this wave's K-chunk base kstep

  __shared__ f32x4 lred[4][10][64];

  float bia[5];
#pragma unroll
  for (int g = 0; g < 5; ++g) bia[g] = bias[g*512 + r0 + l15];

  for (int d = 0; d < 63; ++d) {
    if (d > 0) {
      if (tid == 0) {
        if (leader) {
          while (__hip_atomic_load(&flags2[((d-1)*6 + grp6)*16], __ATOMIC_RELAXED, __HIP_MEMORY_SCOPE_AGENT) < 128)
            __builtin_amdgcn_s_sleep(1);
          __hip_atomic_fetch_add(&flags[d-1], 1, __ATOMIC_RELAXED, __HIP_MEMORY_SCOPE_AGENT);
        }
        while (__hip_atomic_load(&flags[d-1], __ATOMIC_RELAXED, __HIP_MEMORY_SCOPE_AGENT) < 6)
          __builtin_amdgcn_s_sleep(1);
      }
      __syncthreads();
    }
    const int ncell = (d < 32) ? (d + 1) : (63 - d);
    const int i0    = (d < 32) ? 0 : (d - 31);
    const int rprev = ((d-1)&1)*32;

#pragma unroll 1
    for (int rep = 0; rep < 2; ++rep) {
      const int L = cellgroup + rep*24;
      if (L >= ncell) break;                 // block-uniform

      const int i = i0 + L, j = d - i;
      const long cid = (long)i*32 + j;
      const f16 *pxh = xg + cid*8192, *pxl = xg + XG_PLANE + cid*8192;
      const f16 *puh = (i>0) ? (hr + (long)(rprev+i-1)*16384) : zb;
      const f16 *pul = (i>0) ? (hr + HR_PLANE + (long)(rprev+i-1)*16384) : zb;
      const f16 *plh = (j>0) ? (hr + (long)(rprev+i)*16384) : zb;
      const f16 *pll = (j>0) ? (hr + HR_PLANE + (long)(rprev+i)*16384) : zb;

      // hoisted c-ring preloads for epilogue (nt; latency hides under K-loop)
      float cu_r[4], cl_r[4];
      if (wave < 2) {
#pragma unroll
        for (int v = 0; v < 4; ++v) {
          const int off = (wave*16 + l4*4 + v)*512 + r0 + l15;
          cu_r[v] = (i>0) ? ld_ntf(cr + (long)(rprev+i-1)*16384 + off) : 0.0f;
          cl_r[v] = (j>0) ? ld_ntf(cr + (long)(rprev+i)*16384 + off)   : 0.0f;
        }
      }

      f32x4 acc[2][5];
#pragma unroll
      for (int mt = 0; mt < 2; ++mt)
#pragma unroll
        for (int g = 0; g < 5; ++g) acc[mt][g] = (f32x4){0.f,0.f,0.f,0.f};

      f16x8 Bh[5], Bl[5];
      f16x8 c0h, c0l, c1h, c1l, n0h, n0l, n1h, n1l;
      PREFA(kb, c0h, c0l, c1h, c1l);
#pragma unroll
      for (int t = 0; t < 10; t += 2) {
        PREFA(kb+t+1, n0h, n0l, n1h, n1l);
        PREFB(kb+t);
        MFMAS(c0h, c0l, c1h, c1l);
        if (t+2 < 10) PREFA(kb+t+2, c0h, c0l, c1h, c1l);
        PREFB(kb+t+1);
        MFMAS(n0h, n0l, n1h, n1l);
      }

      // ---- LDS reduction of 4 K-chunk partials ----
#pragma unroll
      for (int mt = 0; mt < 2; ++mt)
#pragma unroll
        for (int g = 0; g < 5; ++g)
          lred[wave][mt*5+g][lane] = acc[mt][g];
      __syncthreads();

      if (wave < 2) {
        f32x4 sum[5];
#pragma unroll
        for (int g = 0; g < 5; ++g)
          sum[g] = lred[0][wave*5+g][lane] + lred[1][wave*5+g][lane]
                 + lred[2][wave*5+g][lane] + lred[3][wave*5+g][lane];

        const long wb = (long)((d&1)*32 + i)*16384;
#pragma unroll
        for (int v = 0; v < 4; ++v) {
          const int brow = wave*16 + l4*4 + v;
          const int off = brow*512 + r0 + l15;
          float zi  = sum[0][v]*SCL + bia[0];
          float zj  = sum[1][v]*SCL + bia[1];
          float zf1 = sum[2][v]*SCL + bia[2];
          float zf2 = sum[3][v]*SCL + bia[3];
          float zo  = sum[4][v]*SCL + bia[4];
          float nc = cu_r[v]*sigf(zf1) + cl_r[v]*sigf(zf2) + sigf(zi)*tanh_fast(zj);
          float nh = tanh_fast(nc)*sigf(zo);
          st_sc_f32(cr + wb + off, nc);
          float nhs = nh * 16.0f;
          f16 hh = (f16)nhs;
          st_sc_f16(hr + wb + off, hh);
          st_sc_f16(hr + HR_PLANE + wb + off, (f16)(nhs - (float)hh));
          __builtin_nontemporal_store(nh, out + (((long)brow*32 + i)*32 + j)*512 + r0 + l15);
        }
      }
      __syncthreads();   // protect lred before next task's writes
    }

    // ---- end of diagonal: drain all vmem (incl. sc stores), then signal ----
    asm volatile("s_waitcnt vmcnt(0)" ::: "memory");
    __syncthreads();
    if (tid == 0)
      __hip_atomic_fetch_add(&flags2[(d*6 + grp6)*16], 1, __ATOMIC_RELAXED, __HIP_MEMORY_SCOPE_AGENT);
  }
}

extern "C" void kernel_launch(void* const* d_in, const int* in_sizes, int n_in,
                              void* d_out, int out_size, void* d_ws, size_t ws_size,
                              hipStream_t stream) {
  const float* x  = (const float*)d_in[0];   // [32,16,128,128]
  const float* Wm = (const float*)d_in[1];   // [1280,2560]
  const float* bs = (const float*)d_in[2];   // [2560]
  float* out = (float*)d_out;                // [32,32,32,512]
  char* ws = (char*)d_ws;                    // needs ~52.7 MiB

  int*   flags  = (int*)(ws + FLAGS_OFF);
  int*   flags2 = (int*)(ws + FLAGS2_OFF);
  f16*   zb     = (f16*)(ws + ZERO_OFF);
  f16*   Bt     = (f16*)(ws + BT_OFF);
  f16*   xgb    = (f16*)(ws + XG_OFF);
  f16*   hrb    = (f16*)(ws + HR_OFF);
  float* crb    = (float*)(ws + CR_OFF);

  hipMemsetAsync(ws, 0, BT_OFF, stream);     // flags + flags2 + zero block
  gather_xg_k<<<32768, 256, 0, stream>>>(x, xgb);
  prep_b_k<<<1600, 256, 0, stream>>>(Wm, Bt);
  mdlstm_wave_k<<<768, 256, 0, stream>>>(Bt, xgb, hrb, crb, bs, zb, out, flags, flags2);
}